// Round 3
// baseline (68.591 us; speedup 1.0000x reference)
//
#include <hip/hip_runtime.h>

// PyramidPooling: 8 graphs, D=256 fp32 features, stable descending counting
// sort by degree (bins 0..99), then pyramid mean-pool over rank ranges for
// levels {1,2,4,8,16}. Output: out[g*7936 + d*31 + slot], fp32.

#define DFEAT 256
#define NPOOL 31

// graph node offsets (cumsum of COUNTS)
static __device__ __constant__ int c_goff[9] =
    {0, 12000, 30000, 55000, 70000, 100000, 122000, 139000, 160000};
// 64-node sort-chunk offsets per graph (ceil(n/64) cumsum)
static __device__ __constant__ int c_coff[9] =
    {0, 188, 470, 861, 1096, 1565, 1909, 2175, 2504};
// 128-rank pool-chunk offsets per graph (ceil(n/128) cumsum)
static __device__ __constant__ int c_poff[9] =
    {0, 94, 235, 431, 549, 784, 956, 1089, 1254};
static __device__ __constant__ int c_lvl[5]    = {1, 2, 4, 8, 16};
static __device__ __constant__ int c_lvloff[5] = {0, 1, 3, 7, 15};

#define NCHUNK 2504
#define NPOOLBLK 1254

// Per-chunk (64 nodes = 1 wave) degree histogram over 100 bins via ballots.
__global__ __launch_bounds__(64) void k_hist(const int* __restrict__ deg,
                                             int* __restrict__ chist) {
    int c = blockIdx.x;
    int l = threadIdx.x;
    int g = 0;
    while (c >= c_coff[g + 1]) ++g;
    int i = c_goff[g] + (c - c_coff[g]) * 64 + l;
    int bin = -1;
    if (i < c_goff[g + 1]) {
        int dg = deg[i];
        bin = dg < 0 ? 0 : (dg > 99 ? 99 : dg);
    }
    int cnt0 = 0, cnt1 = 0;
    for (int v = 0; v < 100; ++v) {
        unsigned long long m = __ballot(bin == v);
        int pc = __popcll(m);
        if (l == v) cnt0 = pc;
        if (l + 64 == v) cnt1 = pc;
    }
    chist[c * 100 + l] = cnt0;
    if (l < 36) chist[c * 100 + 64 + l] = cnt1;
}

// One wave per (graph, bin): exclusive scan over that graph's chunk counts,
// in place (chist becomes per-chunk base w/o start); writes bin totals.
__global__ __launch_bounds__(64) void k_scan(int* __restrict__ chist,
                                             int* __restrict__ totals) {
    int b = blockIdx.x;
    int g = b / 100, k = b % 100;
    int l = threadIdx.x;
    int c0 = c_coff[g], c1 = c_coff[g + 1];
    int running = 0;
    for (int base = c0; base < c1; base += 64) {
        int c = base + l;
        int val = (c < c1) ? chist[c * 100 + k] : 0;
        int incl = val;
        #pragma unroll
        for (int off = 1; off < 64; off <<= 1) {
            int y = __shfl_up(incl, off);
            if (l >= off) incl += y;
        }
        if (c < c1) chist[c * 100 + k] = running + (incl - val);
        running += __shfl(incl, 63);
    }
    if (l == 0) totals[g * 100 + k] = running;
}

// start[g][k] = number of nodes in graph g with bin > k (descending sort).
__global__ __launch_bounds__(128) void k_start(const int* __restrict__ totals,
                                               int* __restrict__ startA) {
    __shared__ int t[100];
    int g = blockIdx.x, k = threadIdx.x;
    if (k < 100) t[k] = totals[g * 100 + k];
    __syncthreads();
    if (k < 100) {
        int s = 0;
        for (int j = k + 1; j < 100; ++j) s += t[j];
        startA[g * 100 + k] = s;
    }
}

// Stable scatter: rank = start + chunk prefix + same-bin-lanes-below.
__global__ __launch_bounds__(64) void k_scatter(const int* __restrict__ deg,
                                                const int* __restrict__ chist,
                                                const int* __restrict__ startA,
                                                int* __restrict__ sidx) {
    int c = blockIdx.x;
    int l = threadIdx.x;
    int g = 0;
    while (c >= c_coff[g + 1]) ++g;
    int i = c_goff[g] + (c - c_coff[g]) * 64 + l;
    bool valid = i < c_goff[g + 1];
    int bin = -1;
    if (valid) {
        int dg = deg[i];
        bin = dg < 0 ? 0 : (dg > 99 ? 99 : dg);
    }
    unsigned long long mymask = 0;
    for (int v = 0; v < 100; ++v) {
        unsigned long long m = __ballot(bin == v);
        if (bin == v) mymask = m;
    }
    if (valid) {
        unsigned long long below = mymask & ((1ull << l) - 1ull);
        int rank = startA[g * 100 + bin] + chist[c * 100 + bin] + __popcll(below);
        sidx[c_goff[g] + rank] = i;  // global node index
    }
}

// Pool v3: block = 128 consecutive ranks (1254 blocks, ~all CU-resident).
// Wave w handles rows s+w, +4, ...; lane loads float4 (64 lanes = full 1KB
// row); 8 independent loads in flight per wave. Segment = boundary-free row
// range: sum once, flush S*invk to all 5 levels via coalesced atomics into
// acc[g][slot][d] (slot-major workspace, L2-resident).
__global__ __launch_bounds__(256) void k_pool(const float* __restrict__ x,
                                              const int* __restrict__ sidx,
                                              float* __restrict__ acc) {
    __shared__ int sIdxSm[128];
    __shared__ float red[1024];
    int b = blockIdx.x;
    int g = 0;
    while (b >= c_poff[g + 1]) ++g;
    int n = c_goff[g + 1] - c_goff[g];
    int r0 = (b - c_poff[g]) * 128;
    int r1 = min(r0 + 128, n);
    int t = threadIdx.x;
    if (t < r1 - r0) sIdxSm[t] = sidx[c_goff[g] + r0 + t];
    __syncthreads();

    const int w = t >> 6;
    const int l = t & 63;

    float invk[5];
    int j[5], nb[5], kk[5];
    #pragma unroll
    for (int lev = 0; lev < 5; ++lev) {
        int p = c_lvl[lev];
        kk[lev] = (n + p - 1) / p;
        invk[lev] = 1.0f / (float)kk[lev];
        j[lev] = r0 / kk[lev];
        nb[lev] = (j[lev] + 1) * kk[lev];
    }
    float* ag = acc + (size_t)g * (DFEAT * NPOOL);

    int s = r0;
    while (s < r1) {
        int send = r1;
        #pragma unroll
        for (int lev = 0; lev < 5; ++lev) send = min(send, nb[lev]);

        float4 a0 = {0, 0, 0, 0}, a1 = {0, 0, 0, 0};
        float4 a2 = {0, 0, 0, 0}, a3 = {0, 0, 0, 0};
        int r = s + w;
        for (; r + 28 < send; r += 32) {
            const float4 v0 = *(const float4*)(x + (size_t)sIdxSm[r      - r0] * DFEAT + l * 4);
            const float4 v1 = *(const float4*)(x + (size_t)sIdxSm[r + 4  - r0] * DFEAT + l * 4);
            const float4 v2 = *(const float4*)(x + (size_t)sIdxSm[r + 8  - r0] * DFEAT + l * 4);
            const float4 v3 = *(const float4*)(x + (size_t)sIdxSm[r + 12 - r0] * DFEAT + l * 4);
            const float4 v4 = *(const float4*)(x + (size_t)sIdxSm[r + 16 - r0] * DFEAT + l * 4);
            const float4 v5 = *(const float4*)(x + (size_t)sIdxSm[r + 20 - r0] * DFEAT + l * 4);
            const float4 v6 = *(const float4*)(x + (size_t)sIdxSm[r + 24 - r0] * DFEAT + l * 4);
            const float4 v7 = *(const float4*)(x + (size_t)sIdxSm[r + 28 - r0] * DFEAT + l * 4);
            a0 += v0; a1 += v1; a2 += v2; a3 += v3;
            a0 += v4; a1 += v5; a2 += v6; a3 += v7;
        }
        for (; r < send; r += 4) {
            a0 += *(const float4*)(x + (size_t)sIdxSm[r - r0] * DFEAT + l * 4);
        }
        a0 += a1; a2 += a3; a0 += a2;
        *(float4*)(red + w * 256 + l * 4) = a0;
        __syncthreads();
        float S = red[t] + red[256 + t] + red[512 + t] + red[768 + t];
        #pragma unroll
        for (int lev = 0; lev < 5; ++lev) {
            atomicAdd(ag + (c_lvloff[lev] + j[lev]) * DFEAT + t, S * invk[lev]);
            if (send == nb[lev]) { j[lev]++; nb[lev] += kk[lev]; }
        }
        s = send;
        __syncthreads();
    }
}

// Transpose acc[g][slot][d] -> out[g][d][slot].
__global__ __launch_bounds__(256) void k_finish(const float* __restrict__ acc,
                                                float* __restrict__ out, int nOut) {
    int i = blockIdx.x * 256 + threadIdx.x;
    if (i < nOut) {
        int g = i / (DFEAT * NPOOL);
        int rem = i % (DFEAT * NPOOL);
        int d = rem / NPOOL;
        int slot = rem % NPOOL;
        out[i] = acc[g * (DFEAT * NPOOL) + slot * DFEAT + d];
    }
}

extern "C" void kernel_launch(void* const* d_in, const int* in_sizes, int n_in,
                              void* d_out, int out_size, void* d_ws, size_t ws_size,
                              hipStream_t stream) {
    const float* x  = (const float*)d_in[0];
    const int* deg  = (const int*)d_in[2];
    float* out      = (float*)d_out;

    int* ws      = (int*)d_ws;
    int* chist   = ws;               // NCHUNK*100 = 250400 ints
    int* totals  = ws + 250400;      // 800 ints
    int* startA  = ws + 251200;      // 800 ints
    int* sidx    = ws + 252000;      // 160000 ints
    float* accb  = (float*)(ws + 412000);  // 63488 floats (~1.9 MB total ws)

    hipMemsetAsync(accb, 0, (size_t)out_size * sizeof(float), stream);
    hipLaunchKernelGGL(k_hist, dim3(NCHUNK), dim3(64), 0, stream, deg, chist);
    hipLaunchKernelGGL(k_scan, dim3(800), dim3(64), 0, stream, chist, totals);
    hipLaunchKernelGGL(k_start, dim3(8), dim3(128), 0, stream, totals, startA);
    hipLaunchKernelGGL(k_scatter, dim3(NCHUNK), dim3(64), 0, stream, deg, chist,
                       startA, sidx);
    hipLaunchKernelGGL(k_pool, dim3(NPOOLBLK), dim3(256), 0, stream, x, sidx, accb);
    hipLaunchKernelGGL(k_finish, dim3((out_size + 255) / 256), dim3(256), 0, stream,
                       accb, out, out_size);
}

// Round 4
// 64.272 us; speedup vs baseline: 1.0672x; 1.0672x over previous
//
#include <hip/hip_runtime.h>

// PyramidPooling: 8 graphs, D=256 fp32 features, stable descending counting
// sort by degree (bins 0..99), then pyramid mean-pool over rank ranges for
// levels {1,2,4,8,16}. Output: out[g*7936 + d*31 + slot], fp32.

#define DFEAT 256
#define NPOOL 31

// graph node offsets (cumsum of COUNTS)
static __device__ __constant__ int c_goff[9] =
    {0, 12000, 30000, 55000, 70000, 100000, 122000, 139000, 160000};
// 64-node sort-chunk offsets per graph (ceil(n/64) cumsum)
static __device__ __constant__ int c_coff[9] =
    {0, 188, 470, 861, 1096, 1565, 1909, 2175, 2504};
// 256-rank pool-chunk offsets per graph (ceil(n/256) cumsum)
static __device__ __constant__ int c_poff[9] =
    {0, 47, 118, 216, 275, 393, 479, 546, 629};
static __device__ __constant__ int c_lvl[5]    = {1, 2, 4, 8, 16};
static __device__ __constant__ int c_lvloff[5] = {0, 1, 3, 7, 15};

#define NCHUNK 2504
#define NPOOLBLK 629

// Per-chunk (64 nodes = 1 wave) degree histogram over 100 bins via ballots.
__global__ __launch_bounds__(64) void k_hist(const int* __restrict__ deg,
                                             int* __restrict__ chist) {
    int c = blockIdx.x;
    int l = threadIdx.x;
    int g = 0;
    while (c >= c_coff[g + 1]) ++g;
    int i = c_goff[g] + (c - c_coff[g]) * 64 + l;
    int bin = -1;
    if (i < c_goff[g + 1]) {
        int dg = deg[i];
        bin = dg < 0 ? 0 : (dg > 99 ? 99 : dg);
    }
    int cnt0 = 0, cnt1 = 0;
    for (int v = 0; v < 100; ++v) {
        unsigned long long m = __ballot(bin == v);
        int pc = __popcll(m);
        if (l == v) cnt0 = pc;
        if (l + 64 == v) cnt1 = pc;
    }
    chist[c * 100 + l] = cnt0;
    if (l < 36) chist[c * 100 + 64 + l] = cnt1;
}

// One wave per (graph, bin): exclusive scan over that graph's chunk counts,
// in place (chist becomes per-chunk base w/o start); writes bin totals.
__global__ __launch_bounds__(64) void k_scan(int* __restrict__ chist,
                                             int* __restrict__ totals) {
    int b = blockIdx.x;
    int g = b / 100, k = b % 100;
    int l = threadIdx.x;
    int c0 = c_coff[g], c1 = c_coff[g + 1];
    int running = 0;
    for (int base = c0; base < c1; base += 64) {
        int c = base + l;
        int val = (c < c1) ? chist[c * 100 + k] : 0;
        int incl = val;
        #pragma unroll
        for (int off = 1; off < 64; off <<= 1) {
            int y = __shfl_up(incl, off);
            if (l >= off) incl += y;
        }
        if (c < c1) chist[c * 100 + k] = running + (incl - val);
        running += __shfl(incl, 63);
    }
    if (l == 0) totals[g * 100 + k] = running;
}

// Stable scatter with fused descending-start: start[bin] = suffix sum of
// totals (computed per block in LDS, ~300 cy << launch overhead of k_start).
__global__ __launch_bounds__(64) void k_scatter(const int* __restrict__ deg,
                                                const int* __restrict__ chist,
                                                const int* __restrict__ totals,
                                                int* __restrict__ sidx) {
    __shared__ int t[100];
    __shared__ int ssum[100];
    int c = blockIdx.x;
    int l = threadIdx.x;
    int g = 0;
    while (c >= c_coff[g + 1]) ++g;

    t[l] = totals[g * 100 + l];
    if (l < 36) t[64 + l] = totals[g * 100 + 64 + l];
    __syncthreads();
    {
        int s1 = 0;
        for (int j2 = l + 1; j2 < 100; ++j2) s1 += t[j2];
        ssum[l] = s1;
        if (l < 36) {
            int s2 = 0;
            for (int j2 = l + 65; j2 < 100; ++j2) s2 += t[j2];
            ssum[64 + l] = s2;
        }
    }
    __syncthreads();

    int i = c_goff[g] + (c - c_coff[g]) * 64 + l;
    bool valid = i < c_goff[g + 1];
    int bin = -1;
    if (valid) {
        int dg = deg[i];
        bin = dg < 0 ? 0 : (dg > 99 ? 99 : dg);
    }
    unsigned long long mymask = 0;
    for (int v = 0; v < 100; ++v) {
        unsigned long long m = __ballot(bin == v);
        if (bin == v) mymask = m;
    }
    if (valid) {
        unsigned long long below = mymask & ((1ull << l) - 1ull);
        int rank = ssum[bin] + chist[c * 100 + bin] + __popcll(below);
        sidx[c_goff[g] + rank] = i;  // global node index
    }
}

// Pool v4: block = 256 consecutive ranks (629 blocks). Wave w handles rows
// s+w, +4, ...; lane loads float4 (64 lanes = full 1KB row); 8 independent
// loads in flight per wave (64 rows/wave/chunk = 2 unrolled iterations).
// Segment = boundary-free row range: sum once, flush S*invk to all 5 levels
// via coalesced atomics into acc[g][slot][d] (slot-major, L2-resident).
__global__ __launch_bounds__(256) void k_pool(const float* __restrict__ x,
                                              const int* __restrict__ sidx,
                                              float* __restrict__ acc) {
    __shared__ int sIdxSm[256];
    __shared__ float red[1024];
    int b = blockIdx.x;
    int g = 0;
    while (b >= c_poff[g + 1]) ++g;
    int n = c_goff[g + 1] - c_goff[g];
    int r0 = (b - c_poff[g]) * 256;
    int r1 = min(r0 + 256, n);
    int t = threadIdx.x;
    if (t < r1 - r0) sIdxSm[t] = sidx[c_goff[g] + r0 + t];
    __syncthreads();

    const int w = t >> 6;
    const int l = t & 63;

    float invk[5];
    int j[5], nb[5], kk[5];
    #pragma unroll
    for (int lev = 0; lev < 5; ++lev) {
        int p = c_lvl[lev];
        kk[lev] = (n + p - 1) / p;
        invk[lev] = 1.0f / (float)kk[lev];
        j[lev] = r0 / kk[lev];
        nb[lev] = (j[lev] + 1) * kk[lev];
    }
    float* ag = acc + (size_t)g * (DFEAT * NPOOL);

    int s = r0;
    while (s < r1) {
        int send = r1;
        #pragma unroll
        for (int lev = 0; lev < 5; ++lev) send = min(send, nb[lev]);

        float4 a0 = {0, 0, 0, 0}, a1 = {0, 0, 0, 0};
        float4 a2 = {0, 0, 0, 0}, a3 = {0, 0, 0, 0};
        int r = s + w;
        for (; r + 28 < send; r += 32) {
            const float4 v0 = *(const float4*)(x + (size_t)sIdxSm[r      - r0] * DFEAT + l * 4);
            const float4 v1 = *(const float4*)(x + (size_t)sIdxSm[r + 4  - r0] * DFEAT + l * 4);
            const float4 v2 = *(const float4*)(x + (size_t)sIdxSm[r + 8  - r0] * DFEAT + l * 4);
            const float4 v3 = *(const float4*)(x + (size_t)sIdxSm[r + 12 - r0] * DFEAT + l * 4);
            const float4 v4 = *(const float4*)(x + (size_t)sIdxSm[r + 16 - r0] * DFEAT + l * 4);
            const float4 v5 = *(const float4*)(x + (size_t)sIdxSm[r + 20 - r0] * DFEAT + l * 4);
            const float4 v6 = *(const float4*)(x + (size_t)sIdxSm[r + 24 - r0] * DFEAT + l * 4);
            const float4 v7 = *(const float4*)(x + (size_t)sIdxSm[r + 28 - r0] * DFEAT + l * 4);
            a0 += v0; a1 += v1; a2 += v2; a3 += v3;
            a0 += v4; a1 += v5; a2 += v6; a3 += v7;
        }
        for (; r < send; r += 4) {
            a0 += *(const float4*)(x + (size_t)sIdxSm[r - r0] * DFEAT + l * 4);
        }
        a0 += a1; a2 += a3; a0 += a2;
        *(float4*)(red + w * 256 + l * 4) = a0;
        __syncthreads();
        float S = red[t] + red[256 + t] + red[512 + t] + red[768 + t];
        #pragma unroll
        for (int lev = 0; lev < 5; ++lev) {
            atomicAdd(ag + (c_lvloff[lev] + j[lev]) * DFEAT + t, S * invk[lev]);
            if (send == nb[lev]) { j[lev]++; nb[lev] += kk[lev]; }
        }
        s = send;
        __syncthreads();
    }
}

// Transpose acc[g][slot][d] -> out[g][d][slot].
__global__ __launch_bounds__(256) void k_finish(const float* __restrict__ acc,
                                                float* __restrict__ out, int nOut) {
    int i = blockIdx.x * 256 + threadIdx.x;
    if (i < nOut) {
        int g = i / (DFEAT * NPOOL);
        int rem = i % (DFEAT * NPOOL);
        int d = rem / NPOOL;
        int slot = rem % NPOOL;
        out[i] = acc[g * (DFEAT * NPOOL) + slot * DFEAT + d];
    }
}

extern "C" void kernel_launch(void* const* d_in, const int* in_sizes, int n_in,
                              void* d_out, int out_size, void* d_ws, size_t ws_size,
                              hipStream_t stream) {
    const float* x  = (const float*)d_in[0];
    const int* deg  = (const int*)d_in[2];
    float* out      = (float*)d_out;

    int* ws      = (int*)d_ws;
    int* chist   = ws;               // NCHUNK*100 = 250400 ints
    int* totals  = ws + 250400;      // 800 ints
    int* sidx    = ws + 252000;      // 160000 ints
    float* accb  = (float*)(ws + 412000);  // 63488 floats (~1.9 MB total ws)

    hipMemsetAsync(accb, 0, (size_t)out_size * sizeof(float), stream);
    hipLaunchKernelGGL(k_hist, dim3(NCHUNK), dim3(64), 0, stream, deg, chist);
    hipLaunchKernelGGL(k_scan, dim3(800), dim3(64), 0, stream, chist, totals);
    hipLaunchKernelGGL(k_scatter, dim3(NCHUNK), dim3(64), 0, stream, deg, chist,
                       totals, sidx);
    hipLaunchKernelGGL(k_pool, dim3(NPOOLBLK), dim3(256), 0, stream, x, sidx, accb);
    hipLaunchKernelGGL(k_finish, dim3((out_size + 255) / 256), dim3(256), 0, stream,
                       accb, out, out_size);
}

// Round 5
// 54.338 us; speedup vs baseline: 1.2623x; 1.1828x over previous
//
#include <hip/hip_runtime.h>

// PyramidPooling: 8 graphs, D=256 fp32 features, stable descending counting
// sort by degree (bins 0..99), then pyramid mean-pool over rank ranges for
// levels {1,2,4,8,16}. Output: out[g*7936 + d*31 + slot], fp32.

#define DFEAT 256
#define NPOOL 31

// graph node offsets (cumsum of COUNTS)
static __device__ __constant__ int c_goff[9] =
    {0, 12000, 30000, 55000, 70000, 100000, 122000, 139000, 160000};
// 256-node chunk offsets per graph (ceil(n/256) cumsum) — used by sort AND pool
static __device__ __constant__ int c_poff[9] =
    {0, 47, 118, 216, 275, 393, 479, 546, 629};
static __device__ __constant__ int c_lvl[5]    = {1, 2, 4, 8, 16};
static __device__ __constant__ int c_lvloff[5] = {0, 1, 3, 7, 15};

#define NCHUNK 629   // 256-node chunks
#define NACC 63488   // 8*256*31

// Per-chunk histogram (256 nodes, 4 waves; per-wave ballots + LDS combine).
// Blocks 0..247 also zero the acc buffer (folds the memset node).
__global__ __launch_bounds__(256) void k_hist(const int* __restrict__ deg,
                                              int* __restrict__ chist,
                                              float* __restrict__ accb) {
    __shared__ int whist[4][100];
    int c = blockIdx.x;
    int t = threadIdx.x;
    if (c < 248) accb[c * 256 + t] = 0.0f;
    int w = t >> 6, l = t & 63;
    int g = 0;
    while (c >= c_poff[g + 1]) ++g;
    int i = c_goff[g] + (c - c_poff[g]) * 256 + t;
    int bin = -1;
    if (i < c_goff[g + 1]) {
        int dg = deg[i];
        bin = dg < 0 ? 0 : (dg > 99 ? 99 : dg);
    }
    int cnt0 = 0, cnt1 = 0;
    for (int v = 0; v < 100; ++v) {
        unsigned long long m = __ballot(bin == v);
        int pc = __popcll(m);
        if (l == v) cnt0 = pc;
        if (l + 64 == v) cnt1 = pc;
    }
    whist[w][l] = cnt0;
    if (l < 36) whist[w][64 + l] = cnt1;
    __syncthreads();
    if (t < 100)
        chist[c * 100 + t] = whist[0][t] + whist[1][t] + whist[2][t] + whist[3][t];
}

// One wave per (graph, bin): exclusive scan over that graph's chunk counts
// (<=118 chunks -> <=2 iterations), in place; writes bin totals.
__global__ __launch_bounds__(64) void k_scan(int* __restrict__ chist,
                                             int* __restrict__ totals) {
    int b = blockIdx.x;
    int g = b / 100, k = b % 100;
    int l = threadIdx.x;
    int c0 = c_poff[g], c1 = c_poff[g + 1];
    int running = 0;
    for (int base = c0; base < c1; base += 64) {
        int c = base + l;
        int val = (c < c1) ? chist[c * 100 + k] : 0;
        int incl = val;
        #pragma unroll
        for (int off = 1; off < 64; off <<= 1) {
            int y = __shfl_up(incl, off);
            if (l >= off) incl += y;
        }
        if (c < c1) chist[c * 100 + k] = running + (incl - val);
        running += __shfl(incl, 63);
    }
    if (l == 0) totals[g * 100 + k] = running;
}

// Stable scatter (256-node chunks): rank = suffix-sum start (descending) +
// chunk base (scanned chist) + cross-wave prefix (LDS) + lanes-below (ballot).
__global__ __launch_bounds__(256) void k_scatter(const int* __restrict__ deg,
                                                 const int* __restrict__ chist,
                                                 const int* __restrict__ totals,
                                                 int* __restrict__ sidx) {
    __shared__ int tt[100];
    __shared__ int ssum[100];
    __shared__ int whist[4][100];
    int c = blockIdx.x;
    int t = threadIdx.x;
    int w = t >> 6, l = t & 63;
    int g = 0;
    while (c >= c_poff[g + 1]) ++g;

    if (t < 100) tt[t] = totals[g * 100 + t];
    __syncthreads();
    if (t < 100) {
        int s = 0;
        for (int j2 = t + 1; j2 < 100; ++j2) s += tt[j2];
        ssum[t] = s;
    }

    int i = c_goff[g] + (c - c_poff[g]) * 256 + t;
    bool valid = i < c_goff[g + 1];
    int bin = -1;
    if (valid) {
        int dg = deg[i];
        bin = dg < 0 ? 0 : (dg > 99 ? 99 : dg);
    }
    unsigned long long mymask = 0;
    int cnt0 = 0, cnt1 = 0;
    for (int v = 0; v < 100; ++v) {
        unsigned long long m = __ballot(bin == v);
        int pc = __popcll(m);
        if (bin == v) mymask = m;
        if (l == v) cnt0 = pc;
        if (l + 64 == v) cnt1 = pc;
    }
    whist[w][l] = cnt0;
    if (l < 36) whist[w][64 + l] = cnt1;
    __syncthreads();

    if (valid) {
        int wpre = 0;
        for (int w2 = 0; w2 < 4; ++w2)
            if (w2 < w) wpre += whist[w2][bin];
        unsigned long long below = mymask & ((1ull << l) - 1ull);
        int rank = ssum[bin] + chist[c * 100 + bin] + wpre + __popcll(below);
        sidx[c_goff[g] + rank] = i;  // global node index
    }
}

// Pool (round-2 proven form): block = 256 consecutive ranks (629 blocks).
// Wave w handles rows s+w, +4, ...; lane loads float4 (64 lanes = full 1KB
// row), 4 independent loads in flight. Segment = boundary-free row range:
// sum once, flush S*invk to all 5 levels via coalesced atomics into
// acc[g][slot][d] (slot-major, L2-resident).
__global__ __launch_bounds__(256) void k_pool(const float* __restrict__ x,
                                              const int* __restrict__ sidx,
                                              float* __restrict__ acc) {
    __shared__ int sIdxSm[256];
    __shared__ float red[1024];
    int b = blockIdx.x;
    int g = 0;
    while (b >= c_poff[g + 1]) ++g;
    int n = c_goff[g + 1] - c_goff[g];
    int r0 = (b - c_poff[g]) * 256;
    int r1 = min(r0 + 256, n);
    int t = threadIdx.x;
    if (t < r1 - r0) sIdxSm[t] = sidx[c_goff[g] + r0 + t];
    __syncthreads();

    const int w = t >> 6;
    const int l = t & 63;

    float invk[5];
    int j[5], nb[5], kk[5];
    #pragma unroll
    for (int lev = 0; lev < 5; ++lev) {
        int p = c_lvl[lev];
        kk[lev] = (n + p - 1) / p;
        invk[lev] = 1.0f / (float)kk[lev];
        j[lev] = r0 / kk[lev];
        nb[lev] = (j[lev] + 1) * kk[lev];
    }
    float* ag = acc + (size_t)g * (DFEAT * NPOOL);

    int s = r0;
    while (s < r1) {
        int send = r1;
        #pragma unroll
        for (int lev = 0; lev < 5; ++lev) send = min(send, nb[lev]);

        float4 a0 = {0, 0, 0, 0}, a1 = {0, 0, 0, 0};
        float4 a2 = {0, 0, 0, 0}, a3 = {0, 0, 0, 0};
        int r = s + w;
        for (; r + 12 < send; r += 16) {
            const float4 v0 = *(const float4*)(x + (size_t)sIdxSm[r      - r0] * DFEAT + l * 4);
            const float4 v1 = *(const float4*)(x + (size_t)sIdxSm[r + 4  - r0] * DFEAT + l * 4);
            const float4 v2 = *(const float4*)(x + (size_t)sIdxSm[r + 8  - r0] * DFEAT + l * 4);
            const float4 v3 = *(const float4*)(x + (size_t)sIdxSm[r + 12 - r0] * DFEAT + l * 4);
            a0 += v0; a1 += v1; a2 += v2; a3 += v3;
        }
        for (; r < send; r += 4) {
            a0 += *(const float4*)(x + (size_t)sIdxSm[r - r0] * DFEAT + l * 4);
        }
        a0 += a1; a2 += a3; a0 += a2;
        *(float4*)(red + w * 256 + l * 4) = a0;
        __syncthreads();
        float S = red[t] + red[256 + t] + red[512 + t] + red[768 + t];
        #pragma unroll
        for (int lev = 0; lev < 5; ++lev) {
            atomicAdd(ag + (c_lvloff[lev] + j[lev]) * DFEAT + t, S * invk[lev]);
            if (send == nb[lev]) { j[lev]++; nb[lev] += kk[lev]; }
        }
        s = send;
        __syncthreads();
    }
}

// Transpose acc[g][slot][d] -> out[g][d][slot].
__global__ __launch_bounds__(256) void k_finish(const float* __restrict__ acc,
                                                float* __restrict__ out, int nOut) {
    int i = blockIdx.x * 256 + threadIdx.x;
    if (i < nOut) {
        int g = i / (DFEAT * NPOOL);
        int rem = i % (DFEAT * NPOOL);
        int d = rem / NPOOL;
        int slot = rem % NPOOL;
        out[i] = acc[g * (DFEAT * NPOOL) + slot * DFEAT + d];
    }
}

extern "C" void kernel_launch(void* const* d_in, const int* in_sizes, int n_in,
                              void* d_out, int out_size, void* d_ws, size_t ws_size,
                              hipStream_t stream) {
    const float* x  = (const float*)d_in[0];
    const int* deg  = (const int*)d_in[2];
    float* out      = (float*)d_out;

    int* ws      = (int*)d_ws;
    int* chist   = ws;               // NCHUNK*100 = 62900 ints
    int* totals  = ws + 62900;       // 800 ints
    int* sidx    = ws + 63700;       // 160000 ints
    float* accb  = (float*)(ws + 223700);  // 63488 floats (~1.15 MB total ws)

    hipLaunchKernelGGL(k_hist, dim3(NCHUNK), dim3(256), 0, stream, deg, chist, accb);
    hipLaunchKernelGGL(k_scan, dim3(800), dim3(64), 0, stream, chist, totals);
    hipLaunchKernelGGL(k_scatter, dim3(NCHUNK), dim3(256), 0, stream, deg, chist,
                       totals, sidx);
    hipLaunchKernelGGL(k_pool, dim3(NCHUNK), dim3(256), 0, stream, x, sidx, accb);
    hipLaunchKernelGGL(k_finish, dim3((out_size + 255) / 256), dim3(256), 0, stream,
                       accb, out, out_size);
}